// Round 1
// baseline (130.614 us; speedup 1.0000x reference)
//
#include <hip/hip_runtime.h>

// Single-layer LSTM, input_size=1, hidden_size=1, zero init state.
// x: [B, T, 1] f32; w_ih: [4] (i,f,g,o); w_hh: [4]; b_ih: [4]; b_hh: [4].
// out: [B, T, 1] f32 (the h sequence).
//
// One thread per batch row; strictly serial over T within the thread.
// All sigmoid/tanh computed via v_exp_f32 (2^x) with the log2e scale
// folded into precomputed per-gate coefficients so the recurrent
// critical path is: fma -> exp2 -> add -> rcp -> fma -> exp2 -> rcp -> fma -> mul.

#define LOG2E 1.44269504088896340736f

__global__ __launch_bounds__(64) void lstm_h1_kernel(
    const float* __restrict__ x,
    const float* __restrict__ w_ih,
    const float* __restrict__ w_hh,
    const float* __restrict__ b_ih,
    const float* __restrict__ b_hh,
    float* __restrict__ out,
    int B, int T)
{
    int row = blockIdx.x * blockDim.x + threadIdx.x;
    if (row >= B) return;

    // Gate order: i, f, g, o. Combined bias.
    float b0 = b_ih[0] + b_hh[0];
    float b1 = b_ih[1] + b_hh[1];
    float b2 = b_ih[2] + b_hh[2];
    float b3 = b_ih[3] + b_hh[3];
    float wi0 = w_ih[0], wi1 = w_ih[1], wi2 = w_ih[2], wi3 = w_ih[3];
    float wh0 = w_hh[0], wh1 = w_hh[1], wh2 = w_hh[2], wh3 = w_hh[3];

    // Folded coefficients:
    // sigmoid(z) = 1/(1+2^(-L z)); gate z = wi*x + b + wh*h
    //   u = fma(x, -L*wi, -L*b) then u = fma(h, -L*wh, u)
    // tanh(z) = 2/(1+2^(-2L z)) - 1 (gate g): scale by -2L instead.
    const float ciw = -LOG2E * wi0, cib = -LOG2E * b0, cih = -LOG2E * wh0;
    const float cfw = -LOG2E * wi1, cfb = -LOG2E * b1, cfh = -LOG2E * wh1;
    const float cgw = -2.0f * LOG2E * wi2, cgb = -2.0f * LOG2E * b2, cgh = -2.0f * LOG2E * wh2;
    const float cow = -LOG2E * wi3, cob = -LOG2E * b3, coh = -LOG2E * wh3;
    const float n2L = -2.0f * LOG2E;

    float h = 0.0f, c = 0.0f;

    const float4* __restrict__ xr = reinterpret_cast<const float4*>(x + (size_t)row * T);
    float4* __restrict__ yr = reinterpret_cast<float4*>(out + (size_t)row * T);

    const int nT4 = T >> 2;
    for (int t4 = 0; t4 < nT4; ++t4) {
        float4 xv = xr[t4];
        float xs[4] = {xv.x, xv.y, xv.z, xv.w};
        float hs[4];
        #pragma unroll
        for (int j = 0; j < 4; ++j) {
            float xx = xs[j];
            // x-dependent parts (off the critical path; can issue early)
            float ai = fmaf(xx, ciw, cib);
            float af = fmaf(xx, cfw, cfb);
            float ag = fmaf(xx, cgw, cgb);
            float ao = fmaf(xx, cow, cob);
            // h-dependent gate pre-activations (scaled)
            float ui = fmaf(h, cih, ai);
            float uf = fmaf(h, cfh, af);
            float ug = fmaf(h, cgh, ag);
            float uo = fmaf(h, coh, ao);
            float ei = __builtin_amdgcn_exp2f(ui);
            float ef = __builtin_amdgcn_exp2f(uf);
            float eg = __builtin_amdgcn_exp2f(ug);
            float eo = __builtin_amdgcn_exp2f(uo);
            float si = __builtin_amdgcn_rcpf(1.0f + ei);   // sigmoid(i)
            float sf = __builtin_amdgcn_rcpf(1.0f + ef);   // sigmoid(f)
            float g  = fmaf(2.0f, __builtin_amdgcn_rcpf(1.0f + eg), -1.0f); // tanh(g)
            float so = __builtin_amdgcn_rcpf(1.0f + eo);   // sigmoid(o)
            c = fmaf(sf, c, si * g);
            float ec = __builtin_amdgcn_exp2f(n2L * c);
            float tc = fmaf(2.0f, __builtin_amdgcn_rcpf(1.0f + ec), -1.0f); // tanh(c)
            h = so * tc;
            hs[j] = h;
        }
        float4 hv;
        hv.x = hs[0]; hv.y = hs[1]; hv.z = hs[2]; hv.w = hs[3];
        yr[t4] = hv;
    }
}

extern "C" void kernel_launch(void* const* d_in, const int* in_sizes, int n_in,
                              void* d_out, int out_size, void* d_ws, size_t ws_size,
                              hipStream_t stream) {
    const float* x    = (const float*)d_in[0];
    const float* w_ih = (const float*)d_in[1];
    const float* w_hh = (const float*)d_in[2];
    const float* b_ih = (const float*)d_in[3];
    const float* b_hh = (const float*)d_in[4];
    float* out = (float*)d_out;

    const int T = 1024;
    const int B = in_sizes[0] / T;  // x has B*T*1 elements

    const int block = 64;
    const int grid = (B + block - 1) / block;
    lstm_h1_kernel<<<grid, block, 0, stream>>>(x, w_ih, w_hh, b_ih, b_hh, out, B, T);
}

// Round 3
// 94.613 us; speedup vs baseline: 1.3805x; 1.3805x over previous
//
#include <hip/hip_runtime.h>

// Single-layer LSTM, input_size=1, hidden_size=1, zero init state.
// x: [B, T, 1] f32; w_ih: [4] (i,f,g,o); w_hh: [4]; b_ih: [4]; b_hh: [4].
// out: [B, T, 1] f32 (the h sequence).
//
// One thread per batch row, strictly serial over T. Latency-chain bound:
//  - software prefetch (depth-4 float4 rotation) hides ~900cy HBM latency
//  - recurrent chain ~11 ops/step:
//      u = fma(tc_prev, p, a)   [p = wh' * so_prev computed off-chain]
//      -> exp2 -> add -> rcp -> (sf path) -> cs fma -> exp2 -> add -> rcp -> tc fma
//    cs tracks (-2*log2e)*c so tanh(c) = 2*rcp(1+exp2(cs)) - 1 with no extra mul.
//
// R2 bug fix: g2 = n2L*tanh(zg) = c2n*rg + cnn  (was c2n*rg - cnn: double negation).

#define LOG2E 1.44269504088896340736f

__global__ __launch_bounds__(64) void lstm_h1_kernel(
    const float* __restrict__ x,
    const float* __restrict__ w_ih,
    const float* __restrict__ w_hh,
    const float* __restrict__ b_ih,
    const float* __restrict__ b_hh,
    float* __restrict__ out,
    int B, int T)
{
    int row = blockIdx.x * blockDim.x + threadIdx.x;
    if (row >= B) return;

    // Gate order: i, f, g, o. Combined bias.
    float b0 = b_ih[0] + b_hh[0];
    float b1 = b_ih[1] + b_hh[1];
    float b2 = b_ih[2] + b_hh[2];
    float b3 = b_ih[3] + b_hh[3];
    float wi0 = w_ih[0], wi1 = w_ih[1], wi2 = w_ih[2], wi3 = w_ih[3];
    float wh0 = w_hh[0], wh1 = w_hh[1], wh2 = w_hh[2], wh3 = w_hh[3];

    // Scaled coefficients. Sigmoid gates scale by -L, tanh gate by -2L.
    const float ciw = -LOG2E * wi0,        cib = -LOG2E * b0,        cih = -LOG2E * wh0;
    const float cfw = -LOG2E * wi1,        cfb = -LOG2E * b1,        cfh = -LOG2E * wh1;
    const float cgw = -2.0f * LOG2E * wi2, cgb = -2.0f * LOG2E * b2, cgh = -2.0f * LOG2E * wh2;
    const float cow = -LOG2E * wi3,        cob = -LOG2E * b3,        coh = -LOG2E * wh3;
    const float n2L  = -2.0f * LOG2E;       // cs = n2L * c
    const float c2n  = 2.0f * n2L;          // g2 = c2n*rg + cnn  (= n2L * tanh(zg))
    const float cnn  = -n2L;

    // Recurrent state: tc = tanh(c_prev), cs = n2L*c_prev, p* = c*h coeff * sigmoid(o_prev).
    // h0 = 0  =>  tc=0 makes fma(tc,p,a)=a regardless of p.
    float tc = 0.0f, cs = 0.0f;
    float pio = 0.0f, pfo = 0.0f, pgo = 0.0f, poo = 0.0f;

    const float4* __restrict__ xr = reinterpret_cast<const float4*>(x + (size_t)row * T);
    float4* __restrict__ yr = reinterpret_cast<float4*>(out + (size_t)row * T);

    const int nT4 = T >> 2;  // 256

    // Depth-4 prefetch pipeline.
    float4 p0 = xr[0];
    float4 p1 = xr[1];
    float4 p2 = xr[2];
    float4 p3 = xr[3];

    #pragma unroll 4
    for (int t4 = 0; t4 < nT4; ++t4) {
        float4 xv = p0;
        p0 = p1; p1 = p2; p2 = p3;
        int nidx = t4 + 4;
        nidx = nidx < nT4 ? nidx : (nT4 - 1);   // clamp: safe, branch-free
        p3 = xr[nidx];

        float xs[4] = {xv.x, xv.y, xv.z, xv.w};
        float hs[4];
        #pragma unroll
        for (int j = 0; j < 4; ++j) {
            float xx = xs[j];
            // x-dependent pre-activations (independent of recurrence).
            float ai = fmaf(xx, ciw, cib);
            float af = fmaf(xx, cfw, cfb);
            float ag = fmaf(xx, cgw, cgb);
            float ao = fmaf(xx, cow, cob);
            // Recurrent pre-activations: u = a + wh'*h = fma(tc, p, a).
            float ui = fmaf(tc, pio, ai);
            float uf = fmaf(tc, pfo, af);
            float ug = fmaf(tc, pgo, ag);
            float uo = fmaf(tc, poo, ao);
            float ei = __builtin_amdgcn_exp2f(ui);
            float ef = __builtin_amdgcn_exp2f(uf);
            float eg = __builtin_amdgcn_exp2f(ug);
            float eo = __builtin_amdgcn_exp2f(uo);
            float si = __builtin_amdgcn_rcpf(1.0f + ei);   // sigmoid(zi)
            float sf = __builtin_amdgcn_rcpf(1.0f + ef);   // sigmoid(zf)
            float rg = __builtin_amdgcn_rcpf(1.0f + eg);   // sigmoid(2*zg)
            float so = __builtin_amdgcn_rcpf(1.0f + eo);   // sigmoid(zo)
            // Off-chain: next step's recurrent coefficients (hide under tanh(c) pipe).
            pio = cih * so;
            pfo = cfh * so;
            pgo = cgh * so;
            poo = coh * so;
            // g2 = n2L * tanh(zg) = c2n*rg + cnn
            float g2 = fmaf(c2n, rg, cnn);
            // cs = n2L*c : cs_new = sf*cs + si*g2
            cs = fmaf(sf, cs, si * g2);
            float ec = __builtin_amdgcn_exp2f(cs);
            float rc = __builtin_amdgcn_rcpf(1.0f + ec);
            tc = fmaf(2.0f, rc, -1.0f);            // tanh(c_new)
            hs[j] = so * tc;                        // h (output only; off-chain)
        }
        float4 hv;
        hv.x = hs[0]; hv.y = hs[1]; hv.z = hs[2]; hv.w = hs[3];
        yr[t4] = hv;
    }
}

extern "C" void kernel_launch(void* const* d_in, const int* in_sizes, int n_in,
                              void* d_out, int out_size, void* d_ws, size_t ws_size,
                              hipStream_t stream) {
    const float* x    = (const float*)d_in[0];
    const float* w_ih = (const float*)d_in[1];
    const float* w_hh = (const float*)d_in[2];
    const float* b_ih = (const float*)d_in[3];
    const float* b_hh = (const float*)d_in[4];
    float* out = (float*)d_out;

    const int T = 1024;
    const int B = in_sizes[0] / T;  // x has B*T*1 elements

    const int block = 64;
    const int grid = (B + block - 1) / block;
    lstm_h1_kernel<<<grid, block, 0, stream>>>(x, w_ih, w_hh, b_ih, b_hh, out, B, T);
}